// Round 5
// baseline (167.252 us; speedup 1.0000x reference)
//
#include <hip/hip_runtime.h>
#include <math.h>
#include <stdint.h>

#define NN 7
#define HD 128
#define FIN 32
#define TPB 8            // tokens per block = 4 waves x 2
#define LN_EPS 1e-5f
#define ALPHA 0.2f
#define NEG_CONST -9e15f
#define SCALE 0.08838834764831845f  // 128^-0.5

typedef __bf16 bf16x8 __attribute__((ext_vector_type(8)));
typedef float  f32x4  __attribute__((ext_vector_type(4)));

// intra-wave LDS ordering: drain LDS queue; "memory" clobber stops reordering
#define FENCE() asm volatile("s_waitcnt lgkmcnt(0)" ::: "memory")

__device__ __forceinline__ uint16_t f2bf_u(float f) {
    union { float f; uint32_t u; } v; v.f = f;
    uint32_t r = v.u + 0x7FFFu + ((v.u >> 16) & 1u);  // RNE
    return (uint16_t)(r >> 16);
}

// ws layout (bytes): WpT[7*128][32] bf16 @0 | W1T[128][128] bf16 @57344
// | W2T[128][128] bf16 @90112 | vab[2][2][128] f32 @122880
#define WS_W1T  57344
#define WS_W2T  90112
#define WS_VAB  122880

__global__ __launch_bounds__(256) void prep_weights(
    const float* __restrict__ Wp,
    const float* __restrict__ W1, const float* __restrict__ a1,
    const float* __restrict__ W2, const float* __restrict__ a2,
    uint16_t* __restrict__ WpT, uint16_t* __restrict__ W1T,
    uint16_t* __restrict__ W2T, float* __restrict__ vab)
{
    const int bid = blockIdx.x, tid = threadIdx.x;
    if (bid < 112) {                 // WpT[gc][f] = Wp[f][gc]
        int idx = bid * 256 + tid;
        int gc = idx >> 5, f = idx & 31;
        WpT[idx] = f2bf_u(Wp[(size_t)f * (NN * HD) + gc]);
    } else if (bid < 176) {          // W1T[c][k] = W1[k][c]
        int idx = (bid - 112) * 256 + tid;
        int c = idx >> 7, k = idx & 127;
        W1T[idx] = f2bf_u(W1[(size_t)k * HD + c]);
    } else if (bid < 240) {          // W2T[c][k] = W2[k][c]
        int idx = (bid - 176) * 256 + tid;
        int c = idx >> 7, k = idx & 127;
        W2T[idx] = f2bf_u(W2[(size_t)k * HD + c]);
    } else {                         // vab[l][which][j] = sum_o W[j][o]*a[which*128+o]
        for (int d = tid; d < 512; d += 256) {
            int l = d >> 8, which = (d >> 7) & 1, j = d & 127;
            const float* W = l ? W2 : W1;
            const float* a = (l ? a2 : a1) + which * HD;
            const float* row = W + (size_t)j * HD;
            float acc = 0.f;
            #pragma unroll 8
            for (int o = 0; o < HD; o += 4) {
                f32x4 wv = *reinterpret_cast<const f32x4*>(&row[o]);
                acc += wv[0]*a[o] + wv[1]*a[o+1] + wv[2]*a[o+2] + wv[3]*a[o+3];
            }
            vab[d] = acc;
        }
    }
}

__global__ __launch_bounds__(256, 3) void gat_fused(
    const float* __restrict__ x, const float* __restrict__ adj,
    const float* __restrict__ bp,
    const uint16_t* __restrict__ WpT, const uint16_t* __restrict__ W1T,
    const uint16_t* __restrict__ W2T, const float* __restrict__ vab,
    const float* __restrict__ g1, const float* __restrict__ b1,
    const float* __restrict__ g2, const float* __restrict__ b2,
    float* __restrict__ out, int BT)
{
    // wave-private slices; NO __syncthreads anywhere
    __shared__ __align__(16) float    h_s[4][14][132];  // 29568 B fp32 residual
    __shared__ __align__(16) uint16_t g_s[4][16][136];  // 17408 B bf16 A-operand
    // total 46976 B -> 3 blocks/CU

    const int tid  = threadIdx.x;
    const int lane = tid & 63;
    const int wave = tid >> 6;
    const int frow = lane & 15;
    const int kgrp = lane >> 4;
    const int kb   = kgrp * 8;
    const int t0w  = blockIdx.x * TPB + wave * 2;   // 2 tokens per wave

    float*    hw = &h_s[wave][0][0];
    uint16_t* gw = &g_s[wave][0][0];

    // zero g pad rows 14,15 (34 x 16B)
    if (lane < 34)
        *reinterpret_cast<f32x4*>((char*)gw + 14 * 272 + lane * 16) = (f32x4){0.f,0.f,0.f,0.f};

    // ---- build x B-fragment in registers: B[k=f][n=token], cols 0..1 valid ----
    bf16x8 bx;
    {
        union { bf16x8 v; uint32_t u[4]; } bu;
        bu.u[0] = bu.u[1] = bu.u[2] = bu.u[3] = 0;
        int tok = t0w + frow;
        if (frow < 2 && tok < BT) {
            f32x4 xa = *reinterpret_cast<const f32x4*>(&x[(size_t)tok * FIN + kb]);
            f32x4 xb = *reinterpret_cast<const f32x4*>(&x[(size_t)tok * FIN + kb + 4]);
            bu.u[0] = (uint32_t)f2bf_u(xa[0]) | ((uint32_t)f2bf_u(xa[1]) << 16);
            bu.u[1] = (uint32_t)f2bf_u(xa[2]) | ((uint32_t)f2bf_u(xa[3]) << 16);
            bu.u[2] = (uint32_t)f2bf_u(xb[0]) | ((uint32_t)f2bf_u(xb[1]) << 16);
            bu.u[3] = (uint32_t)f2bf_u(xb[2]) | ((uint32_t)f2bf_u(xb[3]) << 16);
        }
        bx = bu.v;
    }

    // ---- projection: A = WpT tiles (M=16 out-cols), B = x -> h rows in LDS ----
    {
        const int tok = t0w + frow;
        const bool act = (frow < 2) && (tok < BT);
        #pragma unroll 8
        for (int tile = 0; tile < 56; ++tile) {
            bf16x8 av = *reinterpret_cast<const bf16x8*>(WpT + (size_t)(tile * 16 + frow) * FIN + kb);
            f32x4 acc = {0.f, 0.f, 0.f, 0.f};
            acc = __builtin_amdgcn_mfma_f32_16x16x32_bf16(av, bx, acc, 0, 0, 0);
            if (act) {
                int c0 = tile * 16 + kgrp * 4;
                int n  = c0 >> 7, kk = c0 & 127;
                f32x4 bias = *reinterpret_cast<const f32x4*>(&bp[c0]);
                f32x4 v = {acc[0]+bias[0], acc[1]+bias[1], acc[2]+bias[2], acc[3]+bias[3]};
                *reinterpret_cast<f32x4*>(hw + (frow * NN + n) * 132 + kk) = v;
            }
        }
    }
    FENCE();

    for (int l = 0; l < 2; ++l) {
        const uint16_t* __restrict__ WT = l ? W2T : W1T;
        const float* __restrict__ va = vab + l * 256;
        const float* __restrict__ vb = va + HD;
        const float* __restrict__ gg = l ? g2 : g1;
        const float* __restrict__ bb = l ? b2 : b1;

        // ---- f-dots: lanes 0..13 -> fs(row=lane), lanes 16..29 -> fd(row=lane-16)
        float facc = 0.f;
        {
            int rrow = (lane < 14) ? lane : ((lane >= 16 && lane < 30) ? lane - 16 : -1);
            const float* vv = (lane < 16) ? va : vb;
            if (rrow >= 0) {
                const float* hr = hw + rrow * 132;
                #pragma unroll
                for (int i = 0; i < 32; ++i) {
                    f32x4 hv = *reinterpret_cast<const f32x4*>(hr + i * 4);
                    f32x4 vf = *reinterpret_cast<const f32x4*>(vv + i * 4);
                    facc += hv[0]*vf[0] + hv[1]*vf[1] + hv[2]*vf[2] + hv[3]*vf[3];
                }
            }
        }

        // ---- softmax rows: shfl gathers with FULL EXEC (inactive-lane shfl is
        //      undefined on AMD); lanes >=14 compute harmless garbage ----
        float p[NN];
        {
            const bool sm_act = (lane < 14);
            const int  lt     = (sm_act && lane >= NN) ? 1 : 0;
            const int  inode  = sm_act ? (lane - lt * NN) : 0;
            float e[NN];
            float m = -INFINITY;
            #pragma unroll
            for (int j = 0; j < NN; ++j) {
                float fdj = __shfl(facc, 16 + lt * NN + j, 64);   // all lanes active
                float v = facc + fdj;
                v = (v > 0.f ? v : ALPHA * v) * SCALE;
                v = (adj[inode * NN + j] > 0.f) ? v : NEG_CONST;
                e[j] = v;
                m = fmaxf(m, v);
            }
            float ssum = 0.f;
            #pragma unroll
            for (int j = 0; j < NN; ++j) { e[j] = __expf(e[j] - m); ssum += e[j]; }
            float inv = 1.f / ssum;
            #pragma unroll
            for (int j = 0; j < NN; ++j) p[j] = e[j] * inv;
        }

        // ---- g = att @ h : lane (gm=lane>>2 row, gsub=lane&3 col-quarter) ----
        {
            int gm = lane >> 2, gsub = lane & 3;
            int gt = (gm >= NN) ? 1 : 0;
            f32x4 gacc[8];
            #pragma unroll
            for (int i = 0; i < 8; ++i) gacc[i] = (f32x4){0.f,0.f,0.f,0.f};
            #pragma unroll
            for (int j = 0; j < NN; ++j) {
                float pj = __shfl(p[j], gm, 64);                  // all lanes active
                const float* hr = hw + (gt * NN + j) * 132;
                #pragma unroll
                for (int i = 0; i < 8; ++i) {
                    f32x4 hv = *reinterpret_cast<const f32x4*>(hr + (gsub + 4 * i) * 4);
                    gacc[i][0] += pj * hv[0];
                    gacc[i][1] += pj * hv[1];
                    gacc[i][2] += pj * hv[2];
                    gacc[i][3] += pj * hv[3];
                }
            }
            if (gm < 14) {
                #pragma unroll
                for (int i = 0; i < 8; ++i) {
                    uint32_t u0 = (uint32_t)f2bf_u(gacc[i][0]) | ((uint32_t)f2bf_u(gacc[i][1]) << 16);
                    uint32_t u1 = (uint32_t)f2bf_u(gacc[i][2]) | ((uint32_t)f2bf_u(gacc[i][3]) << 16);
                    uint2 uu = {u0, u1};
                    *reinterpret_cast<uint2*>((char*)gw + gm * 272 + 8 * gsub + 32 * i) = uu;
                }
            }
        }
        FENCE();

        // ---- GEMM: hp = g @ W ; A from wave-private LDS, B from global ----
        f32x4 Cacc[8];
        {
            bf16x8 av4[4];
            #pragma unroll
            for (int ks = 0; ks < 4; ++ks)
                av4[ks] = *reinterpret_cast<const bf16x8*>((char*)gw + frow * 272 + (ks * 32 + kb) * 2);
            #pragma unroll
            for (int ntl = 0; ntl < 8; ++ntl) {
                const uint16_t* bpg = WT + (size_t)(ntl * 16 + frow) * HD + kb;
                f32x4 acc = {0.f, 0.f, 0.f, 0.f};
                #pragma unroll
                for (int ks = 0; ks < 4; ++ks) {
                    bf16x8 bv = *reinterpret_cast<const bf16x8*>(bpg + ks * 32);
                    acc = __builtin_amdgcn_mfma_f32_16x16x32_bf16(av4[ks], bv, acc, 0, 0, 0);
                }
                Cacc[ntl] = acc;
            }
        }

        // ---- LayerNorm + residual (RMW into hw) ----
        {
            float mean4[4], rinv4[4];
            #pragma unroll
            for (int r = 0; r < 4; ++r) {
                float s = 0.f, sq = 0.f;
                #pragma unroll
                for (int q = 0; q < 8; ++q) { float c = Cacc[q][r]; s += c; sq += c * c; }
                #pragma unroll
                for (int msk = 1; msk <= 8; msk <<= 1) {
                    s  += __shfl_xor(s,  msk, 64);
                    sq += __shfl_xor(sq, msk, 64);
                }
                float mean = s * (1.f / HD);
                float var  = sq * (1.f / HD) - mean * mean;
                mean4[r] = mean;
                rinv4[r] = rsqrtf(var + LN_EPS);
            }
            #pragma unroll
            for (int q = 0; q < 8; ++q) {
                int col = q * 16 + frow;
                float gv = gg[col], bv = bb[col];
                #pragma unroll
                for (int r = 0; r < 4; ++r) {
                    int m = kgrp * 4 + r;
                    if (m < 14)
                        hw[m * 132 + col] += (Cacc[q][r] - mean4[r]) * rinv4[r] * gv + bv;
                }
            }
        }
        FENCE();
    }

    // ---- out = mean over nodes (2 tokens per wave) ----
    {
        int t = lane >> 5, c4 = (lane & 31) * 4;
        int tok = t0w + t;
        if (tok < BT) {
            f32x4 s = {0.f, 0.f, 0.f, 0.f};
            #pragma unroll
            for (int n = 0; n < NN; ++n) {
                f32x4 hv = *reinterpret_cast<const f32x4*>(hw + (t * NN + n) * 132 + c4);
                s[0] += hv[0]; s[1] += hv[1]; s[2] += hv[2]; s[3] += hv[3];
            }
            const float inv7 = 1.f / 7.f;
            f32x4 o = {s[0]*inv7, s[1]*inv7, s[2]*inv7, s[3]*inv7};
            *reinterpret_cast<f32x4*>(&out[(size_t)tok * HD + c4]) = o;
        }
    }
}

extern "C" void kernel_launch(void* const* d_in, const int* in_sizes, int n_in,
                              void* d_out, int out_size, void* d_ws, size_t ws_size,
                              hipStream_t stream) {
    const float* x   = (const float*)d_in[0];
    const float* adj = (const float*)d_in[1];
    const float* Wp  = (const float*)d_in[2];
    const float* bp  = (const float*)d_in[3];
    const float* W1  = (const float*)d_in[4];
    const float* a1  = (const float*)d_in[5];
    const float* g1  = (const float*)d_in[6];
    const float* b1  = (const float*)d_in[7];
    const float* W2  = (const float*)d_in[8];
    const float* a2  = (const float*)d_in[9];
    const float* g2  = (const float*)d_in[10];
    const float* b2  = (const float*)d_in[11];
    const int BT = in_sizes[0] / FIN;
    const int blocks = (BT + TPB - 1) / TPB;

    uint8_t* ws = (uint8_t*)d_ws;
    uint16_t* WpT = (uint16_t*)(ws);
    uint16_t* W1T = (uint16_t*)(ws + WS_W1T);
    uint16_t* W2T = (uint16_t*)(ws + WS_W2T);
    float*    vab = (float*)   (ws + WS_VAB);

    prep_weights<<<dim3(241), dim3(256), 0, stream>>>(Wp, W1, a1, W2, a2,
                                                      WpT, W1T, W2T, vab);
    gat_fused<<<dim3(blocks), dim3(256), 0, stream>>>(
        x, adj, bp, WpT, W1T, W2T, vab, g1, b1, g2, b2, (float*)d_out, BT);
}

// Round 6
// 110.561 us; speedup vs baseline: 1.5128x; 1.5128x over previous
//
#include <hip/hip_runtime.h>
#include <math.h>
#include <stdint.h>

#define NN 7
#define HD 128
#define FIN 32
#define TPB 8            // 8 tokens per block; 4 waves, each owns 2 tokens
#define LN_EPS 1e-5f
#define ALPHA 0.2f
#define NEG_CONST -9e15f
#define SCALE 0.08838834764831845f  // 128^-0.5

typedef __bf16 bf16x8 __attribute__((ext_vector_type(8)));
typedef float  f32x4  __attribute__((ext_vector_type(4)));

// intra-wave LDS ordering; sched_barrier stops hoisting past the wait (rule #18)
#define FENCE() do { asm volatile("s_waitcnt lgkmcnt(0)" ::: "memory"); \
                     __builtin_amdgcn_sched_barrier(0); } while (0)

__device__ __forceinline__ uint16_t f2bf_u(float f) {
    union { float f; uint32_t u; } v; v.f = f;
    uint32_t r = v.u + 0x7FFFu + ((v.u >> 16) & 1u);  // RNE
    return (uint16_t)(r >> 16);
}
__device__ __forceinline__ uint32_t pack2(float a, float b) {
    return (uint32_t)f2bf_u(a) | ((uint32_t)f2bf_u(b) << 16);
}
__device__ __forceinline__ float bflo(uint32_t u) {
    union { uint32_t q; float f; } v; v.q = u << 16; return v.f;
}
__device__ __forceinline__ float bfhi(uint32_t u) {
    union { uint32_t q; float f; } v; v.q = u & 0xffff0000u; return v.f;
}

// ws layout (bytes): WpT[7*128][32] bf16 @0 | W1T[128][128] bf16 @57344
// | W2T[128][128] bf16 @90112 | vab[2][2][128] f32 @122880
#define WS_W1T  57344
#define WS_W2T  90112
#define WS_VAB  122880

__global__ __launch_bounds__(256) void prep_weights(
    const float* __restrict__ Wp,
    const float* __restrict__ W1, const float* __restrict__ a1,
    const float* __restrict__ W2, const float* __restrict__ a2,
    uint16_t* __restrict__ WpT, uint16_t* __restrict__ W1T,
    uint16_t* __restrict__ W2T, float* __restrict__ vab)
{
    const int bid = blockIdx.x, tid = threadIdx.x;
    if (bid < 112) {                 // WpT[gc][f] = Wp[f][gc]
        int idx = bid * 256 + tid;
        int gc = idx >> 5, f = idx & 31;
        WpT[idx] = f2bf_u(Wp[(size_t)f * (NN * HD) + gc]);
    } else if (bid < 176) {          // W1T[c][k] = W1[k][c]
        int idx = (bid - 112) * 256 + tid;
        int c = idx >> 7, k = idx & 127;
        W1T[idx] = f2bf_u(W1[(size_t)k * HD + c]);
    } else if (bid < 240) {          // W2T[c][k] = W2[k][c]
        int idx = (bid - 176) * 256 + tid;
        int c = idx >> 7, k = idx & 127;
        W2T[idx] = f2bf_u(W2[(size_t)k * HD + c]);
    } else {                         // vab[l][which][j] = sum_o W[j][o]*a[which*128+o]
        for (int d = tid; d < 512; d += 256) {
            int l = d >> 8, which = (d >> 7) & 1, j = d & 127;
            const float* W = l ? W2 : W1;
            const float* a = (l ? a2 : a1) + which * HD;
            const float* row = W + (size_t)j * HD;
            float acc = 0.f;
            #pragma unroll 8
            for (int o = 0; o < HD; o += 4) {
                f32x4 wv = *reinterpret_cast<const f32x4*>(&row[o]);
                acc += wv[0]*a[o] + wv[1]*a[o+1] + wv[2]*a[o+2] + wv[3]*a[o+3];
            }
            vab[d] = acc;
        }
    }
}

__global__ __launch_bounds__(256, 5) void gat_fused(
    const float* __restrict__ x, const float* __restrict__ adj,
    const float* __restrict__ bp,
    const uint16_t* __restrict__ WpT, const uint16_t* __restrict__ W1T,
    const uint16_t* __restrict__ W2T, const float* __restrict__ vab,
    const float* __restrict__ g1, const float* __restrict__ b1,
    const float* __restrict__ g2, const float* __restrict__ b2,
    float* __restrict__ out, int BT)
{
    // per-wave slices; ONE __syncthreads (after cooperative projection)
    __shared__ __align__(16) uint16_t h_s[4][14][136];  // bf16 residual, 15232 B
    __shared__ __align__(16) uint16_t g_s[4][16][136];  // bf16 A-operand, 17408 B
    // total 32640 B -> 5 blocks/CU (20 waves/CU)

    const int tid  = threadIdx.x;
    const int lane = tid & 63;
    const int wave = tid >> 6;
    const int frow = lane & 15;
    const int kgrp = lane >> 4;
    const int kb   = kgrp * 8;
    const int t0   = blockIdx.x * TPB;

    // ---- B-frag: x for the block's 8 tokens (B col = token) ----
    bf16x8 bx;
    {
        union { bf16x8 v; uint32_t u[4]; } bu;
        bu.u[0] = bu.u[1] = bu.u[2] = bu.u[3] = 0;
        int tok = t0 + frow;
        if (frow < TPB && tok < BT) {
            f32x4 xa = *reinterpret_cast<const f32x4*>(&x[(size_t)tok * FIN + kb]);
            f32x4 xb = *reinterpret_cast<const f32x4*>(&x[(size_t)tok * FIN + kb + 4]);
            bu.u[0] = pack2(xa[0], xa[1]);
            bu.u[1] = pack2(xa[2], xa[3]);
            bu.u[2] = pack2(xb[0], xb[1]);
            bu.u[3] = pack2(xb[2], xb[3]);
        }
        bx = bu.v;
    }

    // ---- cooperative projection: 14 tiles/wave, h rows written bf16 (cross-wave) ----
    #pragma unroll 2
    for (int i = 0; i < 14; ++i) {
        int tile = wave * 14 + i;
        bf16x8 av = *reinterpret_cast<const bf16x8*>(WpT + (size_t)(tile * 16 + frow) * FIN + kb);
        f32x4 acc = {0.f, 0.f, 0.f, 0.f};
        acc = __builtin_amdgcn_mfma_f32_16x16x32_bf16(av, bx, acc, 0, 0, 0);
        int tok = t0 + frow;                 // C col = token, C row = out-col
        if (frow < TPB && tok < BT) {
            int gc0 = tile * 16 + kgrp * 4;  // 4 consecutive out-cols, same node
            f32x4 bias = *reinterpret_cast<const f32x4*>(&bp[gc0]);
            uint2 uu = { pack2(acc[0] + bias[0], acc[1] + bias[1]),
                         pack2(acc[2] + bias[2], acc[3] + bias[3]) };
            int n = gc0 >> 7, kk = gc0 & 127;
            *reinterpret_cast<uint2*>(&h_s[frow >> 1][(frow & 1) * NN + n][kk]) = uu;
        }
    }
    __syncthreads();   // the only block barrier

    for (int l = 0; l < 2; ++l) {
        const uint16_t* __restrict__ WT  = l ? W2T : W1T;
        const float*    __restrict__ vv0 = vab + l * 256;
        const float*    __restrict__ gg  = l ? g2 : g1;
        const float*    __restrict__ bb  = l ? b2 : b1;

        // ---- phase A: f-dots. slot=lane>>1 (0-13: f_src rows, 16-29: f_dst rows) ----
        float facc = 0.f;
        {
            int slot = lane >> 1, half = lane & 1;
            int which = (slot >> 4) & 1;
            int row = slot & 15; if (row > 13) row = 13;
            const uint32_t* hr = reinterpret_cast<const uint32_t*>(&h_s[wave][row][half * 64]);
            const f32x4* vp = reinterpret_cast<const f32x4*>(vv0 + which * HD + half * 64);
            #pragma unroll
            for (int i2 = 0; i2 < 8; ++i2) {
                uint4 hv = *reinterpret_cast<const uint4*>(hr + i2 * 4);
                f32x4 w0 = vp[2 * i2], w1 = vp[2 * i2 + 1];
                facc += bflo(hv.x)*w0[0] + bfhi(hv.x)*w0[1]
                      + bflo(hv.y)*w0[2] + bfhi(hv.y)*w0[3]
                      + bflo(hv.z)*w1[0] + bfhi(hv.z)*w1[1]
                      + bflo(hv.w)*w1[2] + bfhi(hv.w)*w1[3];
            }
            facc += __shfl_xor(facc, 1, 64);   // combine halves (full EXEC)
        }

        // ---- phase B: softmax, all lanes full-EXEC (shfl sources must be active) ----
        float p[NN];
        {
            int i_n = lane & 15; if (i_n > 13) i_n = 13;
            int nb = (i_n >= NN) ? NN : 0;
            int inode = i_n - nb;
            float fs = __shfl(facc, 2 * i_n, 64);
            float e[NN]; float mx = -INFINITY;
            #pragma unroll
            for (int j = 0; j < NN; ++j) {
                float fd = __shfl(facc, 32 + 2 * (nb + j), 64);
                float v = fs + fd;
                v = (v > 0.f ? v : ALPHA * v) * SCALE;
                v = (adj[inode * NN + j] > 0.f) ? v : NEG_CONST;
                e[j] = v; mx = fmaxf(mx, v);
            }
            float ssum = 0.f;
            #pragma unroll
            for (int j = 0; j < NN; ++j) { e[j] = __expf(e[j] - mx); ssum += e[j]; }
            float inv = 1.f / ssum;
            #pragma unroll
            for (int j = 0; j < NN; ++j) p[j] = e[j] * inv;   // canonical in lanes 0-13
        }

        // ---- phase C: g = att @ h (h rows loaded once, reused over 7 outputs) ----
        {
            int t = lane >> 5, cq = lane & 31;   // cols cq*4..+3
            f32x4 hrow[NN];
            #pragma unroll
            for (int j = 0; j < NN; ++j) {
                uint2 hv = *reinterpret_cast<const uint2*>(&h_s[wave][t * NN + j][cq * 4]);
                hrow[j] = (f32x4){bflo(hv.x), bfhi(hv.x), bflo(hv.y), bfhi(hv.y)};
            }
            #pragma unroll
            for (int n = 0; n < NN; ++n) {
                f32x4 ga = {0.f, 0.f, 0.f, 0.f};
                #pragma unroll
                for (int j = 0; j < NN; ++j) {
                    float pj = __shfl(p[j], t * NN + n, 64);   // full EXEC
                    ga[0] += pj * hrow[j][0]; ga[1] += pj * hrow[j][1];
                    ga[2] += pj * hrow[j][2]; ga[3] += pj * hrow[j][3];
                }
                uint2 uu = { pack2(ga[0], ga[1]), pack2(ga[2], ga[3]) };
                *reinterpret_cast<uint2*>(&g_s[wave][t * NN + n][cq * 4]) = uu;
            }
        }
        FENCE();

        // ---- phase D: GEMM hp = g @ W ; A from wave LDS, B from global (L1/L2-hot) ----
        f32x4 Cacc[8];
        {
            bf16x8 av4[4];
            const char* gbase = reinterpret_cast<const char*>(&g_s[wave][0][0]);
            #pragma unroll
            for (int ks = 0; ks < 4; ++ks)
                av4[ks] = *reinterpret_cast<const bf16x8*>(gbase + frow * 272 + kgrp * 16 + ks * 64);
            #pragma unroll
            for (int ntl = 0; ntl < 8; ++ntl) {
                const uint16_t* bpg = WT + (size_t)(ntl * 16 + frow) * HD + kb;
                f32x4 acc = {0.f, 0.f, 0.f, 0.f};
                #pragma unroll
                for (int ks = 0; ks < 4; ++ks) {
                    bf16x8 bv = *reinterpret_cast<const bf16x8*>(bpg + ks * 32);
                    acc = __builtin_amdgcn_mfma_f32_16x16x32_bf16(av4[ks], bv, acc, 0, 0, 0);
                }
                Cacc[ntl] = acc;
            }
        }

        // ---- phase E: LayerNorm + residual, bf16 RMW on h ----
        {
            float mean4[4], rinv4[4];
            #pragma unroll
            for (int r = 0; r < 4; ++r) {
                float s = 0.f, sq = 0.f;
                #pragma unroll
                for (int q = 0; q < 8; ++q) { float c = Cacc[q][r]; s += c; sq += c * c; }
                #pragma unroll
                for (int mk = 1; mk <= 8; mk <<= 1) {
                    s  += __shfl_xor(s,  mk, 64);
                    sq += __shfl_xor(sq, mk, 64);
                }
                float mean = s * (1.f / HD);
                float var  = sq * (1.f / HD) - mean * mean;
                mean4[r] = mean;
                rinv4[r] = rsqrtf(var + LN_EPS);
            }
            #pragma unroll
            for (int q = 0; q < 8; ++q) {
                int col = q * 16 + frow;
                float gv = gg[col], bv = bb[col];
                #pragma unroll
                for (int r = 0; r < 4; ++r) {
                    int m = kgrp * 4 + r;
                    if (m < 14) {
                        uint16_t* hp = &h_s[wave][m][col];
                        float hold = bflo((uint32_t)*hp);
                        *hp = f2bf_u((Cacc[q][r] - mean4[r]) * rinv4[r] * gv + bv + hold);
                    }
                }
            }
        }
        FENCE();
    }

    // ---- out = mean over nodes (2 tokens per wave) ----
    {
        int t = lane >> 5, cq = lane & 31;
        int tok = t0 + wave * 2 + t;
        if (tok < BT) {
            f32x4 s = {0.f, 0.f, 0.f, 0.f};
            #pragma unroll
            for (int n = 0; n < NN; ++n) {
                uint2 hv = *reinterpret_cast<const uint2*>(&h_s[wave][t * NN + n][cq * 4]);
                s[0] += bflo(hv.x); s[1] += bfhi(hv.x);
                s[2] += bflo(hv.y); s[3] += bfhi(hv.y);
            }
            const float inv7 = 1.f / 7.f;
            f32x4 o = {s[0]*inv7, s[1]*inv7, s[2]*inv7, s[3]*inv7};
            *reinterpret_cast<f32x4*>(&out[(size_t)tok * HD + cq * 4]) = o;
        }
    }
}

extern "C" void kernel_launch(void* const* d_in, const int* in_sizes, int n_in,
                              void* d_out, int out_size, void* d_ws, size_t ws_size,
                              hipStream_t stream) {
    const float* x   = (const float*)d_in[0];
    const float* adj = (const float*)d_in[1];
    const float* Wp  = (const float*)d_in[2];
    const float* bp  = (const float*)d_in[3];
    const float* W1  = (const float*)d_in[4];
    const float* a1  = (const float*)d_in[5];
    const float* g1  = (const float*)d_in[6];
    const float* b1  = (const float*)d_in[7];
    const float* W2  = (const float*)d_in[8];
    const float* a2  = (const float*)d_in[9];
    const float* g2  = (const float*)d_in[10];
    const float* b2  = (const float*)d_in[11];
    const int BT = in_sizes[0] / FIN;
    const int blocks = (BT + TPB - 1) / TPB;

    uint8_t* ws = (uint8_t*)d_ws;
    uint16_t* WpT = (uint16_t*)(ws);
    uint16_t* W1T = (uint16_t*)(ws + WS_W1T);
    uint16_t* W2T = (uint16_t*)(ws + WS_W2T);
    float*    vab = (float*)   (ws + WS_VAB);

    prep_weights<<<dim3(241), dim3(256), 0, stream>>>(Wp, W1, a1, W2, a2,
                                                      WpT, W1T, W2T, vab);
    gat_fused<<<dim3(blocks), dim3(256), 0, stream>>>(
        x, adj, bp, WpT, W1T, W2T, vab, g1, b1, g2, b2, (float*)d_out, BT);
}